// Round 1
// baseline (2513.921 us; speedup 1.0000x reference)
//
#include <hip/hip_runtime.h>

#define NPB 2048   // nodes per batch (N)
#define VD  128    // V = E = H
#define KN  32     // neighbors

// ---------------- device helpers ----------------

__device__ __forceinline__ float gelu_t(float x){
    // jax.nn.gelu approximate=True: 0.5*x*(1+tanh(sqrt(2/pi)*(x+0.044715 x^3)))
    const float k0 = 0.7978845608028654f;
    return 0.5f * x * (1.0f + tanhf(k0 * (x + 0.044715f * x * x * x)));
}

__device__ __forceinline__ void fma16(const float4& xv, const float4& wv, float acc[4][4]){
    acc[0][0] = fmaf(xv.x, wv.x, acc[0][0]);
    acc[0][1] = fmaf(xv.x, wv.y, acc[0][1]);
    acc[0][2] = fmaf(xv.x, wv.z, acc[0][2]);
    acc[0][3] = fmaf(xv.x, wv.w, acc[0][3]);
    acc[1][0] = fmaf(xv.y, wv.x, acc[1][0]);
    acc[1][1] = fmaf(xv.y, wv.y, acc[1][1]);
    acc[1][2] = fmaf(xv.y, wv.z, acc[1][2]);
    acc[1][3] = fmaf(xv.y, wv.w, acc[1][3]);
    acc[2][0] = fmaf(xv.z, wv.x, acc[2][0]);
    acc[2][1] = fmaf(xv.z, wv.y, acc[2][1]);
    acc[2][2] = fmaf(xv.z, wv.z, acc[2][2]);
    acc[2][3] = fmaf(xv.z, wv.w, acc[2][3]);
    acc[3][0] = fmaf(xv.w, wv.x, acc[3][0]);
    acc[3][1] = fmaf(xv.w, wv.y, acc[3][1]);
    acc[3][2] = fmaf(xv.w, wv.z, acc[3][2]);
    acc[3][3] = fmaf(xv.w, wv.w, acc[3][3]);
}

// X: LDS, transposed activations [c][edge], row stride 36 floats (16B-aligned, conflict-reduced)
// w: global, row-major [c][128]
template<int R>
__device__ __forceinline__ void gemm_tile(const float (* __restrict__ X)[36],
                                          const float* __restrict__ w,
                                          int ug, int eg, float acc[4][4]){
    #pragma unroll 4
    for (int c = 0; c < R; ++c){
        const float4 xv = *(const float4*)&X[c][eg * 4];          // 4 edges
        const float4 wv = *(const float4*)(w + c * 128 + ug * 4); // 4 units
        fma16(xv, wv, acc);
    }
}

__device__ __forceinline__ void initacc(const float* b, int ug, float acc[4][4]){
    const float4 bv = *(const float4*)(b + ug * 4);
    #pragma unroll
    for (int ee = 0; ee < 4; ++ee){
        acc[ee][0] = bv.x; acc[ee][1] = bv.y; acc[ee][2] = bv.z; acc[ee][3] = bv.w;
    }
}

// sum across all 256 threads (inactive threads pass 0); all threads must call
__device__ __forceinline__ float blocksum256(float v, float* red){
    #pragma unroll
    for (int off = 32; off >= 1; off >>= 1) v += __shfl_xor(v, off);
    __syncthreads();
    if ((threadIdx.x & 63) == 0) red[threadIdx.x >> 6] = v;
    __syncthreads();
    return red[0] + red[1] + red[2] + red[3];
}

// sum across the 32-lane group sharing one eg (lanes differ only in ug)
__device__ __forceinline__ float redgrp32(float v){
    v += __shfl_xor(v, 1);  v += __shfl_xor(v, 2);  v += __shfl_xor(v, 4);
    v += __shfl_xor(v, 8);  v += __shfl_xor(v, 16);
    return v;
}

// ---------------- kernel 1: node message MLP + LN1 + FF + LN2 ----------------
// one block per node; 256 threads; reads hV (self + gathered) and hE; writes hVout

__global__ void __launch_bounds__(256, 2)
node_ff_kernel(const float* __restrict__ hV, const float* __restrict__ hE,
               const int* __restrict__ topo,
               const float* __restrict__ nw1, const float* __restrict__ nb1,
               const float* __restrict__ nw2, const float* __restrict__ nb2,
               const float* __restrict__ nw3, const float* __restrict__ nb3,
               const float* __restrict__ fw1, const float* __restrict__ fb1,
               const float* __restrict__ fw2, const float* __restrict__ fb2,
               const float* __restrict__ l1s, const float* __restrict__ l1b,
               const float* __restrict__ l2s, const float* __restrict__ l2b,
               float* __restrict__ hVout)
{
    __shared__ __align__(16) float Xt[256][36];   // rows 0..127: hV_j^T, 128..255: hE^T ; later rows 0..127 reused as H2^T
    __shared__ __align__(16) float Ht[128][36];   // H1^T
    __shared__ __align__(16) float dhp[8][128];
    __shared__ float sVi[VD];
    __shared__ float sG[VD];
    __shared__ float base1[VD];
    __shared__ float red[4];
    __shared__ int   sJ[KN];

    const int node  = blockIdx.x;
    const int t     = threadIdx.x;
    const int bbase = (node >> 11) << 11;  // batch base row (N = 2048)
    const float* hVi = hV + (size_t)node * VD;
    const float* hEi = hE + (size_t)node * KN * VD;

    if (t < VD) sVi[t] = hVi[t];
    if (t < KN) sJ[t]  = topo[(size_t)node * KN + t];
    __syncthreads();

    // stage X^T: rows 0..127 <- gathered hV_j, rows 128..255 <- hE
    {
        const int c  = t & 127;
        const int eh = t >> 7;            // 0/1
        #pragma unroll
        for (int p = 0; p < 16; ++p){
            const int e = p * 2 + eh;
            const int j = bbase + sJ[e];
            Xt[c][e]       = hV[(size_t)j * VD + c];
            Xt[128 + c][e] = hEi[(size_t)e * VD + c];
        }
    }
    // base1[h] = nb1[h] + hV_i . nw1[0:128, h]   (shared across all K edges)
    if (t < VD){
        float s = nb1[t];
        #pragma unroll 4
        for (int c = 0; c < VD; ++c) s = fmaf(sVi[c], nw1[c * 128 + t], s);
        base1[t] = s;
    }
    __syncthreads();

    const int ug = t & 31;   // unit group: units ug*4..+3
    const int eg = t >> 5;   // edge group: edges eg*4..+3
    float acc[4][4];

    // GEMM1: X[32x256] @ nw1[128:384, :]  (+base1)
    initacc(base1, ug, acc);
    gemm_tile<256>(Xt, nw1 + 128 * 128, ug, eg, acc);
    #pragma unroll
    for (int uu = 0; uu < 4; ++uu)
        #pragma unroll
        for (int ee = 0; ee < 4; ++ee)
            Ht[ug * 4 + uu][eg * 4 + ee] = gelu_t(acc[ee][uu]);
    __syncthreads();

    // GEMM2: H1 @ nw2
    initacc(nb2, ug, acc);
    gemm_tile<128>(Ht, nw2, ug, eg, acc);
    #pragma unroll
    for (int uu = 0; uu < 4; ++uu)
        #pragma unroll
        for (int ee = 0; ee < 4; ++ee)
            Xt[ug * 4 + uu][eg * 4 + ee] = gelu_t(acc[ee][uu]);  // H2^T overlays X rows 0..127
    __syncthreads();

    // GEMM3: H2 @ nw3
    initacc(nb3, ug, acc);
    gemm_tile<128>(Xt, nw3, ug, eg, acc);

    // dh partial: sum over this thread's 4 edges
    {
        float4 p;
        p.x = acc[0][0] + acc[1][0] + acc[2][0] + acc[3][0];
        p.y = acc[0][1] + acc[1][1] + acc[2][1] + acc[3][1];
        p.z = acc[0][2] + acc[1][2] + acc[2][2] + acc[3][2];
        p.w = acc[0][3] + acc[1][3] + acc[2][3] + acc[3][3];
        *(float4*)&dhp[eg][ug * 4] = p;
    }
    __syncthreads();

    // ---- dh reduce + LN1 ----
    float x1 = 0.f;
    if (t < VD){
        float dh = 0.f;
        #pragma unroll
        for (int g = 0; g < 8; ++g) dh += dhp[g][t];
        x1 = fmaf(0.7071f, sVi[t], dh / 60.0f);
    }
    float mu  = blocksum256(x1, red) * (1.0f / 128.0f);
    float dd  = (t < VD) ? (x1 - mu) : 0.f;
    float var = blocksum256(dd * dd, red) * (1.0f / 128.0f);
    float y1  = 0.f;
    if (t < VD) y1 = dd * rsqrtf(var + 1e-6f) * l1s[t] + l1b[t];
    __syncthreads();
    if (t < VD) sVi[t] = y1;       // LN1 output = FF input & residual
    __syncthreads();

    // ---- FF ----
    float g1 = 0.f;
    if (t < VD){
        float a = fb1[t];
        #pragma unroll 4
        for (int c = 0; c < VD; ++c) a = fmaf(sVi[c], fw1[c * 128 + t], a);
        g1 = gelu_t(a);
    }
    __syncthreads();
    if (t < VD) sG[t] = g1;
    __syncthreads();
    float x2 = 0.f;
    if (t < VD){
        float o = fb2[t];
        #pragma unroll 4
        for (int u = 0; u < VD; ++u) o = fmaf(sG[u], fw2[u * 128 + t], o);
        x2 = fmaf(0.7071f, sVi[t], o);
    }
    float mu2  = blocksum256(x2, red) * (1.0f / 128.0f);
    float d2   = (t < VD) ? (x2 - mu2) : 0.f;
    float var2 = blocksum256(d2 * d2, red) * (1.0f / 128.0f);
    if (t < VD)
        hVout[(size_t)node * VD + t] = d2 * rsqrtf(var2 + 1e-6f) * l2s[t] + l2b[t];
}

// ---------------- kernel 2: edge MLP + LN3 (h_E update, in-place safe) ----------------

__global__ void __launch_bounds__(256, 2)
edge_kernel(const float* __restrict__ hV, const float* hEin, const int* __restrict__ topo,
            const float* __restrict__ w1, const float* __restrict__ b1,
            const float* __restrict__ w2, const float* __restrict__ b2,
            const float* __restrict__ w3, const float* __restrict__ b3,
            const float* __restrict__ ls, const float* __restrict__ lb,
            float* hEout)
{
    __shared__ __align__(16) float Xt[256][36];
    __shared__ __align__(16) float Ht[128][36];
    __shared__ float sVi[VD];
    __shared__ float base1[VD];
    __shared__ int   sJ[KN];

    const int node  = blockIdx.x;
    const int t     = threadIdx.x;
    const int bbase = (node >> 11) << 11;
    const float* hVi = hV + (size_t)node * VD;
    const float* hEi = hEin + (size_t)node * KN * VD;

    if (t < VD) sVi[t] = hVi[t];
    if (t < KN) sJ[t]  = topo[(size_t)node * KN + t];
    __syncthreads();

    {
        const int c  = t & 127;
        const int eh = t >> 7;
        #pragma unroll
        for (int p = 0; p < 16; ++p){
            const int e = p * 2 + eh;
            const int j = bbase + sJ[e];
            Xt[c][e]       = hV[(size_t)j * VD + c];
            Xt[128 + c][e] = hEi[(size_t)e * VD + c];
        }
    }
    if (t < VD){
        float s = b1[t];
        #pragma unroll 4
        for (int c = 0; c < VD; ++c) s = fmaf(sVi[c], w1[c * 128 + t], s);
        base1[t] = s;
    }
    __syncthreads();

    const int ug = t & 31;
    const int eg = t >> 5;
    float acc[4][4];

    initacc(base1, ug, acc);
    gemm_tile<256>(Xt, w1 + 128 * 128, ug, eg, acc);
    #pragma unroll
    for (int uu = 0; uu < 4; ++uu)
        #pragma unroll
        for (int ee = 0; ee < 4; ++ee)
            Ht[ug * 4 + uu][eg * 4 + ee] = gelu_t(acc[ee][uu]);
    __syncthreads();

    initacc(b2, ug, acc);
    gemm_tile<128>(Ht, w2, ug, eg, acc);
    #pragma unroll
    for (int uu = 0; uu < 4; ++uu)
        #pragma unroll
        for (int ee = 0; ee < 4; ++ee)
            Xt[ug * 4 + uu][eg * 4 + ee] = gelu_t(acc[ee][uu]);
    __syncthreads();

    initacc(b3, ug, acc);
    gemm_tile<128>(Xt, w3, ug, eg, acc);

    // residual (original hE still in Xt rows 128..255) + per-edge LN3
    const float4 sv = *(const float4*)(ls + ug * 4);
    const float4 bv = *(const float4*)(lb + ug * 4);
    #pragma unroll
    for (int ee = 0; ee < 4; ++ee){
        const float r0 = Xt[128 + ug * 4 + 0][eg * 4 + ee];
        const float r1 = Xt[128 + ug * 4 + 1][eg * 4 + ee];
        const float r2 = Xt[128 + ug * 4 + 2][eg * 4 + ee];
        const float r3 = Xt[128 + ug * 4 + 3][eg * 4 + ee];
        const float x0 = fmaf(0.7071f, r0, acc[ee][0]);
        const float x1 = fmaf(0.7071f, r1, acc[ee][1]);
        const float x2 = fmaf(0.7071f, r2, acc[ee][2]);
        const float x3 = fmaf(0.7071f, r3, acc[ee][3]);
        const float mu = redgrp32(x0 + x1 + x2 + x3) * (1.0f / 128.0f);
        float v = (x0 - mu) * (x0 - mu) + (x1 - mu) * (x1 - mu)
                + (x2 - mu) * (x2 - mu) + (x3 - mu) * (x3 - mu);
        v = redgrp32(v) * (1.0f / 128.0f);
        const float rstd = rsqrtf(v + 1e-6f);
        float4 o;
        o.x = (x0 - mu) * rstd * sv.x + bv.x;
        o.y = (x1 - mu) * rstd * sv.y + bv.y;
        o.z = (x2 - mu) * rstd * sv.z + bv.z;
        o.w = (x3 - mu) * rstd * sv.w + bv.w;
        *(float4*)&hEout[((size_t)node * KN + eg * 4 + ee) * VD + ug * 4] = o;
    }
}

// ---------------- host ----------------

extern "C" void kernel_launch(void* const* d_in, const int* in_sizes, int n_in,
                              void* d_out, int out_size, void* d_ws, size_t ws_size,
                              hipStream_t stream)
{
    (void)in_sizes; (void)n_in; (void)out_size; (void)ws_size;

    const float* hV0  = (const float*)d_in[0];
    const float* hE0  = (const float*)d_in[1];
    const int*   topo = (const int*)  d_in[2];
    const float* nw1  = (const float*)d_in[3];
    const float* nb1  = (const float*)d_in[4];
    const float* nw2  = (const float*)d_in[5];
    const float* nb2  = (const float*)d_in[6];
    const float* nw3  = (const float*)d_in[7];
    const float* nb3  = (const float*)d_in[8];
    const float* fw1  = (const float*)d_in[9];
    const float* fb1  = (const float*)d_in[10];
    const float* fw2  = (const float*)d_in[11];
    const float* fb2  = (const float*)d_in[12];
    const float* ew1  = (const float*)d_in[13];
    const float* eb1  = (const float*)d_in[14];
    const float* ew2  = (const float*)d_in[15];
    const float* eb2  = (const float*)d_in[16];
    const float* ew3  = (const float*)d_in[17];
    const float* eb3  = (const float*)d_in[18];
    const float* l1s  = (const float*)d_in[19];
    const float* l1b  = (const float*)d_in[20];
    const float* l2s  = (const float*)d_in[21];
    const float* l2b  = (const float*)d_in[22];
    const float* l3s  = (const float*)d_in[23];
    const float* l3b  = (const float*)d_in[24];

    float* out_hV = (float*)d_out;
    float* out_hE = out_hV + (size_t)2 * NPB * VD;
    float* wsV    = (float*)d_ws;                 // needs 2 MB scratch for h_V ping-pong

    const int grid = 2 * NPB;
    for (int l = 0; l < 3; ++l){
        const float* hVin; const float* hEin; float* hVnx;
        if (l == 0)      { hVin = hV0;    hEin = hE0;    hVnx = wsV;    }
        else if (l == 1) { hVin = wsV;    hEin = out_hE; hVnx = out_hV; }
        else             { hVin = out_hV; hEin = out_hE; hVnx = wsV;    }

        node_ff_kernel<<<grid, 256, 0, stream>>>(hVin, hEin, topo,
            nw1 + (size_t)l * 49152, nb1 + l * 128,
            nw2 + (size_t)l * 16384, nb2 + l * 128,
            nw3 + (size_t)l * 16384, nb3 + l * 128,
            fw1 + (size_t)l * 16384, fb1 + l * 128,
            fw2 + (size_t)l * 16384, fb2 + l * 128,
            l1s + l * 128, l1b + l * 128, l2s + l * 128, l2b + l * 128,
            hVnx);

        edge_kernel<<<grid, 256, 0, stream>>>(hVnx, hEin, topo,
            ew1 + (size_t)l * 49152, eb1 + l * 128,
            ew2 + (size_t)l * 16384, eb2 + l * 128,
            ew3 + (size_t)l * 16384, eb3 + l * 128,
            l3s + l * 128, l3b + l * 128,
            out_hE);
    }

    // final h_V lives in ws after layer 2 -> copy into d_out
    hipMemcpyAsync(out_hV, wsV, (size_t)2 * NPB * VD * sizeof(float),
                   hipMemcpyDeviceToDevice, stream);
}

// Round 2
// 1062.329 us; speedup vs baseline: 2.3664x; 2.3664x over previous
//
#include <hip/hip_runtime.h>
#include <hip/hip_bf16.h>

#define NNODES 4096      // B*N
#define MEDGES 131072    // B*N*K
#define RS 0.7071f

typedef __bf16 bf16x8 __attribute__((ext_vector_type(8)));
typedef float  f32x4  __attribute__((ext_vector_type(4)));

__device__ __forceinline__ float gelu_t(float x){
    const float k0 = 0.7978845608028654f;
    return 0.5f * x * (1.0f + tanhf(k0 * (x + 0.044715f * x * x * x)));
}
__device__ __forceinline__ ushort f2bf(float f){
    __hip_bfloat16 b = __float2bfloat16(f);
    return __builtin_bit_cast(ushort, b);
}

// ---------------- pack kernels (run every launch; graph-safe) ----------------

__global__ void pack_acts_kernel(const float* __restrict__ hV, const float* __restrict__ hE,
                                 ushort* __restrict__ hVbf, ushort* __restrict__ hEbf){
    const size_t i0 = (size_t)blockIdx.x * 256 + threadIdx.x;
    const size_t stride = (size_t)gridDim.x * 256;
    for (size_t i = i0; i < 16777216ull; i += stride){
        hEbf[i] = f2bf(hE[i]);
        if (i < 524288ull) hVbf[i] = f2bf(hV[i]);
    }
}

// Wp layout per layer (131072 elems): [n1:32768][e1:32768][n2:16384][n3:16384][e2:16384][e3:16384]
// n1/e1: [col][k 0..255] (k maps to W rows 128..383); others: [col][k 0..127]
__global__ void pack_w_kernel(const float* __restrict__ nw1, const float* __restrict__ nw2,
                              const float* __restrict__ nw3, const float* __restrict__ ew1,
                              const float* __restrict__ ew2, const float* __restrict__ ew3,
                              ushort* __restrict__ Wp){
    const int id = blockIdx.x * 256 + threadIdx.x;          // 0..393215
    const int l = id / 131072, r = id % 131072;
    const float* src; int sidx;
    if (r < 32768){ int col = r >> 8, k = r & 255; src = nw1 + l * 49152; sidx = (128 + k) * 128 + col; }
    else if (r < 65536){ int r2 = r - 32768; int col = r2 >> 8, k = r2 & 255; src = ew1 + l * 49152; sidx = (128 + k) * 128 + col; }
    else {
        int r3 = r - 65536; int m = r3 >> 14; int r4 = r3 & 16383;
        int col = r4 >> 7, k = r4 & 127;
        const float* W = (m == 0) ? nw2 : (m == 1) ? nw3 : (m == 2) ? ew2 : ew3;
        src = W + l * 16384; sidx = k * 128 + col;
    }
    Wp[id] = f2bf(src[sidx]);
}

// ---------------- small fp32 per-node kernels ----------------

__device__ __forceinline__ float bsum128(float v, float* red){
    #pragma unroll
    for (int o = 32; o >= 1; o >>= 1) v += __shfl_xor(v, o);
    __syncthreads();
    if ((threadIdx.x & 63) == 0) red[threadIdx.x >> 6] = v;
    __syncthreads();
    return red[0] + red[1];
}

// base1 for layer-0 node MLP: b1n = nb1 + hV . nw1[0:128,:]
__global__ void __launch_bounds__(128)
b1n0_kernel(const float* __restrict__ hVf, const float* __restrict__ nw1,
            const float* __restrict__ nb1, float* __restrict__ b1n){
    __shared__ float HN[8][132];
    const int u = threadIdx.x;
    const size_t n0 = (size_t)blockIdx.x * 8;
    #pragma unroll
    for (int n = 0; n < 8; ++n) HN[n][u] = hVf[(n0 + n) * 128 + u];
    __syncthreads();
    float a[8];
    #pragma unroll
    for (int n = 0; n < 8; ++n) a[n] = nb1[u];
    for (int c = 0; c < 128; ++c){
        float w = nw1[c * 128 + u];
        #pragma unroll
        for (int n = 0; n < 8; ++n) a[n] = fmaf(HN[n][c], w, a[n]);
    }
    #pragma unroll
    for (int n = 0; n < 8; ++n) b1n[(n0 + n) * 128 + u] = a[n];
}

// node update: x = RS*hV + dh/60 -> LN1 -> FF -> LN2 -> hVnew (fp32+bf16) ; base1e ; base1n(next layer)
__global__ void __launch_bounds__(128)
nu_kernel(const float* __restrict__ hVf, const float* __restrict__ dh,
          const float* __restrict__ l1s, const float* __restrict__ l1b,
          const float* __restrict__ l2s, const float* __restrict__ l2b,
          const float* __restrict__ fw1, const float* __restrict__ fb1,
          const float* __restrict__ fw2, const float* __restrict__ fb2,
          const float* __restrict__ ew1, const float* __restrict__ eb1,
          const float* __restrict__ nw1n, const float* __restrict__ nb1n,
          float* __restrict__ hVf_out, ushort* __restrict__ hVbf,
          float* __restrict__ b1e, float* __restrict__ b1n){
    __shared__ float X1[8][132], G[8][132], HN[8][132];
    __shared__ float red[2];
    const int u = threadIdx.x;
    const size_t n0 = (size_t)blockIdx.x * 8;
    float xv[8], a[8];
    #pragma unroll
    for (int n = 0; n < 8; ++n)
        xv[n] = RS * hVf[(n0 + n) * 128 + u] + dh[(n0 + n) * 128 + u] * (1.f / 60.f);
    #pragma unroll
    for (int n = 0; n < 8; ++n){
        float mu = bsum128(xv[n], red) * (1.f / 128.f);
        float d = xv[n] - mu;
        float var = bsum128(d * d, red) * (1.f / 128.f);
        float y = d * rsqrtf(var + 1e-6f) * l1s[u] + l1b[u];
        X1[n][u] = y; xv[n] = y;
    }
    __syncthreads();
    #pragma unroll
    for (int n = 0; n < 8; ++n) a[n] = fb1[u];
    for (int c = 0; c < 128; ++c){
        float w = fw1[c * 128 + u];
        #pragma unroll
        for (int n = 0; n < 8; ++n) a[n] = fmaf(X1[n][c], w, a[n]);
    }
    #pragma unroll
    for (int n = 0; n < 8; ++n) G[n][u] = gelu_t(a[n]);
    __syncthreads();
    #pragma unroll
    for (int n = 0; n < 8; ++n) a[n] = fb2[u];
    for (int c = 0; c < 128; ++c){
        float w = fw2[c * 128 + u];
        #pragma unroll
        for (int n = 0; n < 8; ++n) a[n] = fmaf(G[n][c], w, a[n]);
    }
    #pragma unroll
    for (int n = 0; n < 8; ++n){
        float x = RS * xv[n] + a[n];
        float mu = bsum128(x, red) * (1.f / 128.f);
        float d = x - mu;
        float var = bsum128(d * d, red) * (1.f / 128.f);
        float hv = d * rsqrtf(var + 1e-6f) * l2s[u] + l2b[u];
        HN[n][u] = hv;
        hVf_out[(n0 + n) * 128 + u] = hv;
        hVbf[(n0 + n) * 128 + u] = f2bf(hv);
    }
    __syncthreads();
    #pragma unroll
    for (int n = 0; n < 8; ++n) a[n] = eb1[u];
    for (int c = 0; c < 128; ++c){
        float w = ew1[c * 128 + u];
        #pragma unroll
        for (int n = 0; n < 8; ++n) a[n] = fmaf(HN[n][c], w, a[n]);
    }
    #pragma unroll
    for (int n = 0; n < 8; ++n) b1e[(n0 + n) * 128 + u] = a[n];
    if (nw1n){
        #pragma unroll
        for (int n = 0; n < 8; ++n) a[n] = nb1n[u];
        for (int c = 0; c < 128; ++c){
            float w = nw1n[c * 128 + u];
            #pragma unroll
            for (int n = 0; n < 8; ++n) a[n] = fmaf(HN[n][c], w, a[n]);
        }
        #pragma unroll
        for (int n = 0; n < 8; ++n) b1n[(n0 + n) * 128 + u] = a[n];
    }
}

// ---------------- the MFMA GEMM ----------------
// C[256 x 128] per block, M = 131072 edges total (512 blocks), 512 threads = 8 waves.
// Wave (wr,wc): wr=wave>>1 rows wr*64..+63 ; wc=wave&1 cols wc*64..+63.
// 16x16x32 bf16 MFMA, 4x4 tiles/wave, K chunked by 64 (NCH chunks).
// LDS: A[256][64]bf16 + B^T[128][64]bf16, 16B-chunk XOR swizzle (c ^= row&7) on write AND read.
// MODE 0: gelu -> bf16 Hout ; MODE 1: sum 32-row groups -> dh (fp32) ; MODE 2: residual+LN3 -> hEf/hEbf.
// GATHER: A = [hVbf[topo] (k 0..127) || hEbf (k 128..255)], C-init = per-node base; else C-init = bias[col].

template<int NCH, int MODE, bool GATHER>
__global__ void __launch_bounds__(512, 1)
gemm_kernel(const ushort* __restrict__ Asrc, const ushort* __restrict__ hVbf,
            const ushort* __restrict__ hEbf, const int* __restrict__ topo,
            const ushort* __restrict__ Bp, const float* __restrict__ cinit,
            ushort* __restrict__ Hout, float* __restrict__ dh,
            const float* __restrict__ hEf_in, float* __restrict__ hEf_out,
            ushort* __restrict__ hEbf_out,
            const float* __restrict__ lnS, const float* __restrict__ lnB)
{
    __shared__ __align__(16) char smem[71680];
    ushort* Abuf = (ushort*)smem;                 // 32768 B
    ushort* Bbuf = (ushort*)(smem + 32768);       // 16384 B
    int*    sJ   = (int*)(smem + 69632);          // 1024 B (above T region)
    float*  sLn  = (float*)(smem + 70656);        // 1024 B

    const int t = threadIdx.x;
    const int lane = t & 63, wave = t >> 6;
    const int wr = wave >> 1, wc = wave & 1;
    const size_t bR = (size_t)blockIdx.x * 256;

    if (GATHER && t < 256){
        int rg = blockIdx.x * 256 + t;
        sJ[t] = topo[rg] + ((rg >> 16) << 11);    // + batch*2048
    }
    if (MODE == 2 && t < 128){ sLn[t] = lnS[t]; sLn[128 + t] = lnB[t]; }
    __syncthreads();

    // accumulator init (bias or per-node base)
    f32x4 acc[4][4];
    {
        const int colb = wc * 64 + (lane & 15);
        #pragma unroll
        for (int rt = 0; rt < 4; ++rt){
            float v4[4];
            #pragma unroll
            for (int ct = 0; ct < 4; ++ct){
                int colg = colb + ct * 16;
                float v;
                if (GATHER){
                    int node = blockIdx.x * 8 + wr * 2 + (rt >> 1);
                    v = cinit[(size_t)node * 128 + colg];
                } else v = cinit[colg];
                v4[ct] = v;
            }
            #pragma unroll
            for (int ct = 0; ct < 4; ++ct){
                f32x4 z = {v4[ct], v4[ct], v4[ct], v4[ct]};
                acc[rt][ct] = z;
            }
        }
    }

    uint4 pa[4]; uint4 pb[2];
    const int arow = t >> 1, ah = t & 1;     // A staging: row, 64B half
    const int bcol = t >> 2, bq = t & 3;     // B staging: col, 32B quarter

    auto loadch = [&](int ch){
        const ushort* s;
        if (GATHER){
            if (ch < 2) s = hVbf + (size_t)sJ[arow] * 128 + (ch & 1) * 64;
            else        s = hEbf + (bR + arow) * 128 + (ch & 1) * 64;
        } else {
            s = Asrc + (bR + arow) * 128 + ch * 64;
        }
        const uint4* s4 = (const uint4*)s;
        #pragma unroll
        for (int i = 0; i < 4; ++i) pa[i] = s4[ah * 4 + i];
        const uint4* b4 = (const uint4*)(Bp + (size_t)bcol * (NCH * 64) + ch * 64);
        #pragma unroll
        for (int i = 0; i < 2; ++i) pb[i] = b4[bq * 2 + i];
    };
    auto writech = [&](){
        #pragma unroll
        for (int i = 0; i < 4; ++i){
            int c = ah * 4 + i;
            *(uint4*)(Abuf + arow * 64 + ((c ^ (arow & 7)) << 3)) = pa[i];
        }
        #pragma unroll
        for (int i = 0; i < 2; ++i){
            int c = bq * 2 + i;
            *(uint4*)(Bbuf + bcol * 64 + ((c ^ (bcol & 7)) << 3)) = pb[i];
        }
    };

    loadch(0); writech(); __syncthreads();

    for (int ch = 0; ch < NCH; ++ch){
        if (ch + 1 < NCH) loadch(ch + 1);        // issue next-chunk loads early (hide HBM/L2 under MFMA)
        #pragma unroll
        for (int ks = 0; ks < 2; ++ks){
            bf16x8 af[4], bfr[4];
            const int cc = ks * 4 + (lane >> 4);
            #pragma unroll
            for (int rt = 0; rt < 4; ++rt){
                int row = wr * 64 + rt * 16 + (lane & 15);
                af[rt] = *(const bf16x8*)(Abuf + row * 64 + ((cc ^ (row & 7)) << 3));
            }
            #pragma unroll
            for (int ct = 0; ct < 4; ++ct){
                int col = wc * 64 + ct * 16 + (lane & 15);
                bfr[ct] = *(const bf16x8*)(Bbuf + col * 64 + ((cc ^ (col & 7)) << 3));
            }
            #pragma unroll
            for (int rt = 0; rt < 4; ++rt)
                #pragma unroll
                for (int ct = 0; ct < 4; ++ct)
                    acc[rt][ct] = __builtin_amdgcn_mfma_f32_16x16x32_bf16(af[rt], bfr[ct], acc[rt][ct], 0, 0, 0);
        }
        __syncthreads();
        if (ch + 1 < NCH){ writech(); __syncthreads(); }
    }

    // ---------------- epilogues ----------------
    if (MODE == 0){
        // gelu -> bf16, via LDS transpose for coalesced stores
        ushort* Tb = (ushort*)smem;              // [256][136] = 69632 B
        #pragma unroll
        for (int rt = 0; rt < 4; ++rt)
            #pragma unroll
            for (int ct = 0; ct < 4; ++ct){
                int col = wc * 64 + ct * 16 + (lane & 15);
                #pragma unroll
                for (int r = 0; r < 4; ++r){
                    int row = wr * 64 + rt * 16 + ((lane >> 4) << 2) + r;
                    Tb[row * 136 + col] = f2bf(gelu_t(acc[rt][ct][r]));
                }
            }
        __syncthreads();
        const int row = t >> 1;
        #pragma unroll
        for (int i = 0; i < 8; ++i){
            int c16 = (t & 1) + 2 * i;
            uint4 v = *(const uint4*)(Tb + row * 136 + c16 * 8);
            *(uint4*)(Hout + (bR + row) * 128 + c16 * 8) = v;
        }
    }

    if (MODE == 1 || MODE == 2){
        float* Tf = (float*)smem;                // [128][132] = 67584 B
        #pragma unroll
        for (int p = 0; p < 2; ++p){
            if ((wr >> 1) == p){
                #pragma unroll
                for (int rt = 0; rt < 4; ++rt)
                    #pragma unroll
                    for (int ct = 0; ct < 4; ++ct){
                        int col = wc * 64 + ct * 16 + (lane & 15);
                        #pragma unroll
                        for (int r = 0; r < 4; ++r){
                            int row = (wr & 1) * 64 + rt * 16 + ((lane >> 4) << 2) + r;
                            Tf[row * 132 + col] = acc[rt][ct][r];
                        }
                    }
            }
            __syncthreads();
            if (MODE == 1){
                // sum each 32-row (per-node) group -> dh
                int col = t & 127, g = t >> 7;   // g in 0..3
                float s = 0.f;
                #pragma unroll 8
                for (int r = 0; r < 32; ++r) s += Tf[(g * 32 + r) * 132 + col];
                dh[((size_t)blockIdx.x * 8 + p * 4 + g) * 128 + col] = s;
            } else {
                // per-edge residual + LN3 -> hEf_out (fp32) + hEbf_out
                #pragma unroll
                for (int rr = 0; rr < 2; ++rr){
                    int row = (t >> 3) + rr * 64;
                    int j = t & 7;
                    size_t rowg = bR + p * 128 + row;
                    const float* tr = Tf + row * 132 + j * 16;
                    const float* ri = hEf_in + rowg * 128 + j * 16;
                    float x[16]; float s = 0.f;
                    #pragma unroll
                    for (int i = 0; i < 16; ++i){ x[i] = RS * ri[i] + tr[i]; s += x[i]; }
                    s += __shfl_xor(s, 1); s += __shfl_xor(s, 2); s += __shfl_xor(s, 4);
                    float mu = s * (1.f / 128.f);
                    float vv = 0.f;
                    #pragma unroll
                    for (int i = 0; i < 16; ++i){ float d = x[i] - mu; vv += d * d; }
                    vv += __shfl_xor(vv, 1); vv += __shfl_xor(vv, 2); vv += __shfl_xor(vv, 4);
                    float rstd = rsqrtf(vv * (1.f / 128.f) + 1e-6f);
                    float o[16];
                    #pragma unroll
                    for (int i = 0; i < 16; ++i){
                        int col = j * 16 + i;
                        o[i] = (x[i] - mu) * rstd * sLn[col] + sLn[128 + col];
                    }
                    #pragma unroll
                    for (int i = 0; i < 4; ++i)
                        *(float4*)(hEf_out + rowg * 128 + j * 16 + i * 4) =
                            make_float4(o[i * 4], o[i * 4 + 1], o[i * 4 + 2], o[i * 4 + 3]);
                    uint4 u0, u1;
                    u0.x = (uint)f2bf(o[0])  | ((uint)f2bf(o[1])  << 16);
                    u0.y = (uint)f2bf(o[2])  | ((uint)f2bf(o[3])  << 16);
                    u0.z = (uint)f2bf(o[4])  | ((uint)f2bf(o[5])  << 16);
                    u0.w = (uint)f2bf(o[6])  | ((uint)f2bf(o[7])  << 16);
                    u1.x = (uint)f2bf(o[8])  | ((uint)f2bf(o[9])  << 16);
                    u1.y = (uint)f2bf(o[10]) | ((uint)f2bf(o[11]) << 16);
                    u1.z = (uint)f2bf(o[12]) | ((uint)f2bf(o[13]) << 16);
                    u1.w = (uint)f2bf(o[14]) | ((uint)f2bf(o[15]) << 16);
                    *(uint4*)(hEbf_out + rowg * 128 + j * 16)     = u0;
                    *(uint4*)(hEbf_out + rowg * 128 + j * 16 + 8) = u1;
                }
            }
            __syncthreads();
        }
    }
}

// ---------------- host ----------------

extern "C" void kernel_launch(void* const* d_in, const int* in_sizes, int n_in,
                              void* d_out, int out_size, void* d_ws, size_t ws_size,
                              hipStream_t stream)
{
    (void)in_sizes; (void)n_in; (void)out_size; (void)ws_size;

    const float* hV0  = (const float*)d_in[0];
    const float* hE0  = (const float*)d_in[1];
    const int*   topo = (const int*)  d_in[2];
    const float* nw1  = (const float*)d_in[3];
    const float* nb1  = (const float*)d_in[4];
    const float* nw2  = (const float*)d_in[5];
    const float* nb2  = (const float*)d_in[6];
    const float* nw3  = (const float*)d_in[7];
    const float* nb3  = (const float*)d_in[8];
    const float* fw1  = (const float*)d_in[9];
    const float* fb1  = (const float*)d_in[10];
    const float* fw2  = (const float*)d_in[11];
    const float* fb2  = (const float*)d_in[12];
    const float* ew1  = (const float*)d_in[13];
    const float* eb1  = (const float*)d_in[14];
    const float* ew2  = (const float*)d_in[15];
    const float* eb2  = (const float*)d_in[16];
    const float* ew3  = (const float*)d_in[17];
    const float* eb3  = (const float*)d_in[18];
    const float* l1s  = (const float*)d_in[19];
    const float* l1b  = (const float*)d_in[20];
    const float* l2s  = (const float*)d_in[21];
    const float* l2b  = (const float*)d_in[22];
    const float* l3s  = (const float*)d_in[23];
    const float* l3b  = (const float*)d_in[24];

    float* out_hV = (float*)d_out;
    float* out_hE = out_hV + 524288;             // 2*2048*128

    char* ws = (char*)d_ws;
    ushort* Hbf   = (ushort*)(ws);               // 32 MB
    ushort* hEbf  = (ushort*)(ws + 33554432);    // 32 MB
    ushort* hVbf  = (ushort*)(ws + 67108864);    // 1 MB
    float*  hVf1  = (float*) (ws + 68157440);    // 2 MB
    float*  hVf2  = (float*) (ws + 70254592);    // 2 MB
    float*  b1n   = (float*) (ws + 72351744);    // 2 MB
    float*  b1e   = (float*) (ws + 74448896);    // 2 MB
    float*  dh    = (float*) (ws + 76546048);    // 2 MB
    ushort* Wp    = (ushort*)(ws + 78643200);    // 768 KB

    pack_acts_kernel<<<2048, 256, 0, stream>>>(hV0, hE0, hVbf, hEbf);
    pack_w_kernel<<<1536, 256, 0, stream>>>(nw1, nw2, nw3, ew1, ew2, ew3, Wp);
    b1n0_kernel<<<512, 128, 0, stream>>>(hV0, nw1, nb1, b1n);

    for (int l = 0; l < 3; ++l){
        const ushort* p_n1 = Wp + (size_t)l * 131072;
        const ushort* p_e1 = p_n1 + 32768;
        const ushort* p_n2 = p_n1 + 65536;
        const ushort* p_n3 = p_n1 + 81920;
        const ushort* p_e2 = p_n1 + 98304;
        const ushort* p_e3 = p_n1 + 114688;

        const float* hVf_cur = (l == 0) ? hV0 : (l == 1) ? hVf1 : hVf2;
        float*       hVf_nxt = (l == 0) ? hVf1 : (l == 1) ? hVf2 : out_hV;
        const float* hEf_in  = (l == 0) ? hE0 : out_hE;

        // node message MLP
        gemm_kernel<4,0,true ><<<512, 512, 0, stream>>>(nullptr, hVbf, hEbf, topo, p_n1, b1n,
            Hbf, nullptr, nullptr, nullptr, nullptr, nullptr, nullptr);
        gemm_kernel<2,0,false><<<512, 512, 0, stream>>>(Hbf, nullptr, nullptr, nullptr, p_n2, nb2 + l*128,
            Hbf, nullptr, nullptr, nullptr, nullptr, nullptr, nullptr);
        gemm_kernel<2,1,false><<<512, 512, 0, stream>>>(Hbf, nullptr, nullptr, nullptr, p_n3, nb3 + l*128,
            nullptr, dh, nullptr, nullptr, nullptr, nullptr, nullptr);

        // node update (LN1 + FF + LN2) + edge-base + next-layer node-base
        nu_kernel<<<512, 128, 0, stream>>>(hVf_cur, dh,
            l1s + l*128, l1b + l*128, l2s + l*128, l2b + l*128,
            fw1 + l*16384, fb1 + l*128, fw2 + l*16384, fb2 + l*128,
            ew1 + (size_t)l*49152, eb1 + l*128,
            (l < 2) ? nw1 + (size_t)(l+1)*49152 : nullptr,
            (l < 2) ? nb1 + (l+1)*128 : nullptr,
            hVf_nxt, hVbf, b1e, b1n);

        // edge MLP + LN3
        gemm_kernel<4,0,true ><<<512, 512, 0, stream>>>(nullptr, hVbf, hEbf, topo, p_e1, b1e,
            Hbf, nullptr, nullptr, nullptr, nullptr, nullptr, nullptr);
        gemm_kernel<2,0,false><<<512, 512, 0, stream>>>(Hbf, nullptr, nullptr, nullptr, p_e2, eb2 + l*128,
            Hbf, nullptr, nullptr, nullptr, nullptr, nullptr, nullptr);
        gemm_kernel<2,2,false><<<512, 512, 0, stream>>>(Hbf, nullptr, nullptr, nullptr, p_e3, eb3 + l*128,
            nullptr, nullptr, hEf_in, out_hE, hEbf, l3s + l*128, l3b + l*128);
    }
}

// Round 7
// 1044.264 us; speedup vs baseline: 2.4074x; 1.0173x over previous
//
#include <hip/hip_runtime.h>
#include <hip/hip_bf16.h>

#define RS 0.7071f

typedef __bf16 bf16x8 __attribute__((ext_vector_type(8)));
typedef float  f32x4  __attribute__((ext_vector_type(4)));

__device__ __forceinline__ float gelu_t(float x){
    const float k0 = 0.7978845608028654f;
    return 0.5f * x * (1.0f + tanhf(k0 * (x + 0.044715f * x * x * x)));
}
__device__ __forceinline__ ushort f2bf(float f){
    __hip_bfloat16 b = __float2bfloat16(f);
    return __builtin_bit_cast(ushort, b);
}

// ---------------- pack kernels ----------------

__global__ void pack_acts_kernel(const float* __restrict__ hV, const float* __restrict__ hE,
                                 ushort* __restrict__ hVbf, ushort* __restrict__ hEbf){
    const size_t i0 = (size_t)blockIdx.x * 256 + threadIdx.x;
    const size_t stride = (size_t)gridDim.x * 256;
    for (size_t i = i0; i < 16777216ull; i += stride){
        hEbf[i] = f2bf(hE[i]);
        if (i < 524288ull) hVbf[i] = f2bf(hV[i]);
    }
}

// Wp per-layer layout (196608 elems):
// n1:0 (k256) | e1:32768 (k256) | n2:65536 | n3:81920 | e2:98304 | e3:114688
// f1:131072 | f2:147456 | n1a:163840 (nw1 rows 0..127) | e1a:180224 (ew1 rows 0..127)
// all [col][k] layout
__global__ void pack_w_kernel(const float* __restrict__ nw1, const float* __restrict__ nw2,
                              const float* __restrict__ nw3, const float* __restrict__ ew1,
                              const float* __restrict__ ew2, const float* __restrict__ ew3,
                              const float* __restrict__ fw1, const float* __restrict__ fw2,
                              ushort* __restrict__ Wp){
    const int id = blockIdx.x * 256 + threadIdx.x;          // < 589824
    const int l = id / 196608, r = id % 196608;
    const float* src; int sidx;
    if (r < 32768){ int col = r >> 8, k = r & 255; src = nw1 + (size_t)l * 49152; sidx = (128 + k) * 128 + col; }
    else if (r < 65536){ int r2 = r - 32768; int col = r2 >> 8, k = r2 & 255; src = ew1 + (size_t)l * 49152; sidx = (128 + k) * 128 + col; }
    else {
        int r3 = r - 65536; int m = r3 >> 14; int r4 = r3 & 16383;
        int col = r4 >> 7, k = r4 & 127;
        const float* W;
        switch (m){
            case 0: W = nw2 + (size_t)l * 16384; break;
            case 1: W = nw3 + (size_t)l * 16384; break;
            case 2: W = ew2 + (size_t)l * 16384; break;
            case 3: W = ew3 + (size_t)l * 16384; break;
            case 4: W = fw1 + (size_t)l * 16384; break;
            case 5: W = fw2 + (size_t)l * 16384; break;
            case 6: W = nw1 + (size_t)l * 49152; break;   // rows 0..127
            default:W = ew1 + (size_t)l * 49152; break;   // rows 0..127
        }
        src = W; sidx = k * 128 + col;
    }
    Wp[id] = f2bf(src[sidx]);
}

// ---------------- LN1 kernel: x = RS*hV + dh/60 -> LN -> X1f + X1bf ----------------

__global__ void __launch_bounds__(256)
ln1_kernel(const float* __restrict__ hVf, const float* __restrict__ dh,
           const float* __restrict__ l1s, const float* __restrict__ l1b,
           float* __restrict__ X1f, ushort* __restrict__ X1bf){
    const int lane = threadIdx.x & 63, w = threadIdx.x >> 6;
    const size_t row = (size_t)blockIdx.x * 4 + w;
    const float2 hv = *(const float2*)(hVf + row * 128 + lane * 2);
    const float2 dv = *(const float2*)(dh  + row * 128 + lane * 2);
    float x0 = fmaf(RS, hv.x, dv.x * (1.f / 60.f));
    float x1 = fmaf(RS, hv.y, dv.y * (1.f / 60.f));
    float s = x0 + x1;
    #pragma unroll
    for (int o = 32; o >= 1; o >>= 1) s += __shfl_xor(s, o);
    const float mu = s * (1.f / 128.f);
    const float d0 = x0 - mu, d1 = x1 - mu;
    float v = d0 * d0 + d1 * d1;
    #pragma unroll
    for (int o = 32; o >= 1; o >>= 1) v += __shfl_xor(v, o);
    const float rstd = rsqrtf(v * (1.f / 128.f) + 1e-6f);
    const float y0 = d0 * rstd * l1s[lane * 2]     + l1b[lane * 2];
    const float y1 = d1 * rstd * l1s[lane * 2 + 1] + l1b[lane * 2 + 1];
    *(float2*)(X1f + row * 128 + lane * 2) = make_float2(y0, y1);
    ((uint*)X1bf)[row * 64 + lane] = (uint)f2bf(y0) | ((uint)f2bf(y1) << 16);
}

// ---------------- the MFMA GEMM ----------------
// C[256 x 128] per block, 512 threads = 8 waves; 16x16x32 bf16 MFMA; 4x4 tiles/wave.
// LDS XOR swizzle (both sides). MODE 0: gelu->bf16 Hout ; MODE 1: 32-row group sum -> dh ;
// MODE 2: x=RS*resid_in+acc -> LN(lnS,lnB) -> lnOut(fp32)+bfOut ; MODE 4: acc -> fOut (fp32).
// GATHER: A = [hVbf[topo] || hEbf], C-init per-node from cinit[node][col]; else C-init = cinit[col].

template<int NCH, int MODE, bool GATHER>
__global__ void __launch_bounds__(512, 1)
gemm_kernel(const ushort* __restrict__ Asrc, const ushort* __restrict__ hVbf,
            const ushort* __restrict__ hEbf, const int* __restrict__ topo,
            const ushort* __restrict__ Bp, const float* __restrict__ cinit,
            ushort* __restrict__ Hout, float* __restrict__ fOut,
            const float* __restrict__ resid_in, float* __restrict__ lnOut,
            ushort* __restrict__ bfOut,
            const float* __restrict__ lnS, const float* __restrict__ lnB)
{
    __shared__ __align__(16) char smem[71680];
    ushort* Abuf = (ushort*)smem;                 // 32768 B
    ushort* Bbuf = (ushort*)(smem + 32768);       // 16384 B
    int*    sJ   = (int*)(smem + 69632);          // 1024 B
    float*  sLn  = (float*)(smem + 70656);        // 1024 B

    const int t = threadIdx.x;
    const int lane = t & 63, wave = t >> 6;
    const int wr = wave >> 1, wc = wave & 1;
    const size_t bR = (size_t)blockIdx.x * 256;

    if (GATHER && t < 256){
        int rg = blockIdx.x * 256 + t;
        sJ[t] = topo[rg] + ((rg >> 16) << 11);    // + batch*2048
    }
    if (MODE == 2 && t < 128){ sLn[t] = lnS[t]; sLn[128 + t] = lnB[t]; }
    __syncthreads();

    f32x4 acc[4][4];
    {
        const int colb = wc * 64 + (lane & 15);
        #pragma unroll
        for (int rt = 0; rt < 4; ++rt){
            #pragma unroll
            for (int ct = 0; ct < 4; ++ct){
                int colg = colb + ct * 16;
                float v;
                if (GATHER){
                    int node = blockIdx.x * 8 + wr * 2 + (rt >> 1);
                    v = cinit[(size_t)node * 128 + colg];
                } else v = cinit[colg];
                f32x4 z = {v, v, v, v};
                acc[rt][ct] = z;
            }
        }
    }

    uint4 pa[4]; uint4 pb[2];
    const int arow = t >> 1, ah = t & 1;
    const int bcol = t >> 2, bq = t & 3;

    auto loadch = [&](int ch){
        const ushort* s;
        if (GATHER){
            if (ch < 2) s = hVbf + (size_t)sJ[arow] * 128 + (ch & 1) * 64;
            else        s = hEbf + (bR + arow) * 128 + (ch & 1) * 64;
        } else {
            s = Asrc + (bR + arow) * 128 + ch * 64;
        }
        const uint4* s4 = (const uint4*)s;
        #pragma unroll
        for (int i = 0; i < 4; ++i) pa[i] = s4[ah * 4 + i];
        const uint4* b4 = (const uint4*)(Bp + (size_t)bcol * (NCH * 64) + ch * 64);
        #pragma unroll
        for (int i = 0; i < 2; ++i) pb[i] = b4[bq * 2 + i];
    };
    auto writech = [&](){
        #pragma unroll
        for (int i = 0; i < 4; ++i){
            int c = ah * 4 + i;
            *(uint4*)(Abuf + arow * 64 + ((c ^ (arow & 7)) << 3)) = pa[i];
        }
        #pragma unroll
        for (int i = 0; i < 2; ++i){
            int c = bq * 2 + i;
            *(uint4*)(Bbuf + bcol * 64 + ((c ^ (bcol & 7)) << 3)) = pb[i];
        }
    };

    loadch(0); writech(); __syncthreads();

    for (int ch = 0; ch < NCH; ++ch){
        if (ch + 1 < NCH) loadch(ch + 1);
        #pragma unroll
        for (int ks = 0; ks < 2; ++ks){
            bf16x8 af[4], bfr[4];
            const int cc = ks * 4 + (lane >> 4);
            #pragma unroll
            for (int rt = 0; rt < 4; ++rt){
                int row = wr * 64 + rt * 16 + (lane & 15);
                af[rt] = *(const bf16x8*)(Abuf + row * 64 + ((cc ^ (row & 7)) << 3));
            }
            #pragma unroll
            for (int ct = 0; ct < 4; ++ct){
                int col = wc * 64 + ct * 16 + (lane & 15);
                bfr[ct] = *(const bf16x8*)(Bbuf + col * 64 + ((cc ^ (col & 7)) << 3));
            }
            #pragma unroll
            for (int rt = 0; rt < 4; ++rt)
                #pragma unroll
                for (int ct = 0; ct < 4; ++ct)
                    acc[rt][ct] = __builtin_amdgcn_mfma_f32_16x16x32_bf16(af[rt], bfr[ct], acc[rt][ct], 0, 0, 0);
        }
        __syncthreads();
        if (ch + 1 < NCH){ writech(); __syncthreads(); }
    }

    // ---------------- epilogues ----------------
    if (MODE == 0){
        ushort* Tb = (ushort*)smem;              // [256][136]
        #pragma unroll
        for (int rt = 0; rt < 4; ++rt)
            #pragma unroll
            for (int ct = 0; ct < 4; ++ct){
                int col = wc * 64 + ct * 16 + (lane & 15);
                #pragma unroll
                for (int r = 0; r < 4; ++r){
                    int row = wr * 64 + rt * 16 + ((lane >> 4) << 2) + r;
                    Tb[row * 136 + col] = f2bf(gelu_t(acc[rt][ct][r]));
                }
            }
        __syncthreads();
        const int row = t >> 1;
        #pragma unroll
        for (int i = 0; i < 8; ++i){
            int c16 = (t & 1) + 2 * i;
            uint4 v = *(const uint4*)(Tb + row * 136 + c16 * 8);
            *(uint4*)(Hout + (bR + row) * 128 + c16 * 8) = v;
        }
    }

    if (MODE == 1 || MODE == 2 || MODE == 4){
        float* Tf = (float*)smem;                // [128][132]
        #pragma unroll
        for (int p = 0; p < 2; ++p){
            if ((wr >> 1) == p){
                #pragma unroll
                for (int rt = 0; rt < 4; ++rt)
                    #pragma unroll
                    for (int ct = 0; ct < 4; ++ct){
                        int col = wc * 64 + ct * 16 + (lane & 15);
                        #pragma unroll
                        for (int r = 0; r < 4; ++r){
                            int row = (wr & 1) * 64 + rt * 16 + ((lane >> 4) << 2) + r;
                            Tf[row * 132 + col] = acc[rt][ct][r];
                        }
                    }
            }
            __syncthreads();
            if (MODE == 1){
                int col = t & 127, g = t >> 7;   // g in 0..3
                float s = 0.f;
                #pragma unroll 8
                for (int r = 0; r < 32; ++r) s += Tf[(g * 32 + r) * 132 + col];
                fOut[((size_t)blockIdx.x * 8 + p * 4 + g) * 128 + col] = s;
            } else if (MODE == 4){
                const int row = t >> 2, q = t & 3;
                #pragma unroll
                for (int i = 0; i < 8; ++i){
                    float4 v = *(const float4*)(Tf + row * 132 + q * 32 + i * 4);
                    *(float4*)(fOut + (bR + p * 128 + row) * 128 + q * 32 + i * 4) = v;
                }
            } else {
                #pragma unroll
                for (int rr = 0; rr < 2; ++rr){
                    int row = (t >> 3) + rr * 64;
                    int j = t & 7;
                    size_t rowg = bR + p * 128 + row;
                    const float* tr = Tf + row * 132 + j * 16;
                    const float* ri = resid_in + rowg * 128 + j * 16;
                    float x[16]; float s = 0.f;
                    #pragma unroll
                    for (int i = 0; i < 16; ++i){ x[i] = fmaf(RS, ri[i], tr[i]); s += x[i]; }
                    s += __shfl_xor(s, 1); s += __shfl_xor(s, 2); s += __shfl_xor(s, 4);
                    float mu = s * (1.f / 128.f);
                    float vv = 0.f;
                    #pragma unroll
                    for (int i = 0; i < 16; ++i){ float d = x[i] - mu; vv += d * d; }
                    vv += __shfl_xor(vv, 1); vv += __shfl_xor(vv, 2); vv += __shfl_xor(vv, 4);
                    float rstd = rsqrtf(vv * (1.f / 128.f) + 1e-6f);
                    float o[16];
                    #pragma unroll
                    for (int i = 0; i < 16; ++i){
                        int col = j * 16 + i;
                        o[i] = (x[i] - mu) * rstd * sLn[col] + sLn[128 + col];
                    }
                    #pragma unroll
                    for (int i = 0; i < 4; ++i)
                        *(float4*)(lnOut + rowg * 128 + j * 16 + i * 4) =
                            make_float4(o[i * 4], o[i * 4 + 1], o[i * 4 + 2], o[i * 4 + 3]);
                    uint4 u0, u1;
                    u0.x = (uint)f2bf(o[0])  | ((uint)f2bf(o[1])  << 16);
                    u0.y = (uint)f2bf(o[2])  | ((uint)f2bf(o[3])  << 16);
                    u0.z = (uint)f2bf(o[4])  | ((uint)f2bf(o[5])  << 16);
                    u0.w = (uint)f2bf(o[6])  | ((uint)f2bf(o[7])  << 16);
                    u1.x = (uint)f2bf(o[8])  | ((uint)f2bf(o[9])  << 16);
                    u1.y = (uint)f2bf(o[10]) | ((uint)f2bf(o[11]) << 16);
                    u1.z = (uint)f2bf(o[12]) | ((uint)f2bf(o[13]) << 16);
                    u1.w = (uint)f2bf(o[14]) | ((uint)f2bf(o[15]) << 16);
                    *(uint4*)(bfOut + rowg * 128 + j * 16)     = u0;
                    *(uint4*)(bfOut + rowg * 128 + j * 16 + 8) = u1;
                }
            }
            __syncthreads();
        }
    }
}

// ---------------- host ----------------

extern "C" void kernel_launch(void* const* d_in, const int* in_sizes, int n_in,
                              void* d_out, int out_size, void* d_ws, size_t ws_size,
                              hipStream_t stream)
{
    (void)in_sizes; (void)n_in; (void)out_size; (void)ws_size;

    const float* hV0  = (const float*)d_in[0];
    const float* hE0  = (const float*)d_in[1];
    const int*   topo = (const int*)  d_in[2];
    const float* nw1  = (const float*)d_in[3];
    const float* nb1  = (const float*)d_in[4];
    const float* nb2  = (const float*)d_in[6];
    const float* nb3  = (const float*)d_in[8];
    const float* fb1  = (const float*)d_in[10];
    const float* fb2  = (const float*)d_in[12];
    const float* eb1  = (const float*)d_in[14];
    const float* eb2  = (const float*)d_in[16];
    const float* eb3  = (const float*)d_in[18];
    const float* l1s  = (const float*)d_in[19];
    const float* l1b  = (const float*)d_in[20];
    const float* l2s  = (const float*)d_in[21];
    const float* l2b  = (const float*)d_in[22];
    const float* l3s  = (const float*)d_in[23];
    const float* l3b  = (const float*)d_in[24];

    float* out_hV = (float*)d_out;
    float* out_hE = out_hV + 524288;             // 2*2048*128

    char* ws = (char*)d_ws;
    ushort* Hbf   = (ushort*)(ws);               // 32 MB (node/edge MLP intermediates)
    ushort* hEbf  = (ushort*)(ws + 33554432);    // 32 MB
    ushort* hVbf  = (ushort*)(ws + 67108864);    // 1 MB
    float*  b1n   = (float*) (ws + 68157440);    // 2 MB
    float*  b1e   = (float*) (ws + 70254592);    // 2 MB
    float*  dh    = (float*) (ws + 72351744);    // 2 MB
    float*  X1f   = (float*) (ws + 74448896);    // 2 MB
    ushort* X1bf  = (ushort*)(ws + 76546048);    // 1 MB
    // Gbf aliases Hbf (ws+0): Hbf's node-MLP contents are dead after the MODE-1 dh GEMM,
    // which completes before FF1 writes Gbf; the edge gather GEMM rewrites Hbf afterwards.
    ushort* Gbf   = (ushort*)(ws);               // 1 MB, aliased
    ushort* Wp    = (ushort*)(ws + 77594624);    // 1.125 MB -> high-water 78,774,272 B (< 79,429,632 proven in R2)

    pack_acts_kernel<<<2048, 256, 0, stream>>>(hV0, hE0, hVbf, hEbf);
    pack_w_kernel<<<2304, 256, 0, stream>>>(nw1, (const float*)d_in[5], (const float*)d_in[7],
                                            (const float*)d_in[13], (const float*)d_in[15],
                                            (const float*)d_in[17], (const float*)d_in[9],
                                            (const float*)d_in[11], Wp);
    // initial b1n = nb1(l0) + hV @ nw1[0:128] (layer 0)
    gemm_kernel<2,4,false><<<16, 512, 0, stream>>>(hVbf, nullptr, nullptr, nullptr,
        Wp + 163840, nb1, nullptr, b1n, nullptr, nullptr, nullptr, nullptr, nullptr);

    for (int l = 0; l < 3; ++l){
        const ushort* pL   = Wp + (size_t)l * 196608;
        const ushort* p_n1 = pL;
        const ushort* p_e1 = pL + 32768;
        const ushort* p_n2 = pL + 65536;
        const ushort* p_n3 = pL + 81920;
        const ushort* p_e2 = pL + 98304;
        const ushort* p_e3 = pL + 114688;
        const ushort* p_f1 = pL + 131072;
        const ushort* p_f2 = pL + 147456;
        const ushort* p_e1a= pL + 180224;

        // fp32 h_V lives in out_hV for every layer (read by ln1 of layer l, written by FF2+LN2 of layer l)
        const float* hVf_cur = (l == 0) ? hV0 : out_hV;
        float*       hVf_nxt = out_hV;
        const float* hEf_in  = (l == 0) ? hE0 : out_hE;

        // node message MLP (M = 131072 edges)
        gemm_kernel<4,0,true ><<<512, 512, 0, stream>>>(nullptr, hVbf, hEbf, topo, p_n1, b1n,
            Hbf, nullptr, nullptr, nullptr, nullptr, nullptr, nullptr);
        gemm_kernel<2,0,false><<<512, 512, 0, stream>>>(Hbf, nullptr, nullptr, nullptr, p_n2, nb2 + l*128,
            Hbf, nullptr, nullptr, nullptr, nullptr, nullptr, nullptr);
        gemm_kernel<2,1,false><<<512, 512, 0, stream>>>(Hbf, nullptr, nullptr, nullptr, p_n3, nb3 + l*128,
            nullptr, dh, nullptr, nullptr, nullptr, nullptr, nullptr);

        // LN1 -> X1 ; FF1 ; FF2+LN2 -> h_V next (fp32 in out_hV + bf16 in hVbf)
        ln1_kernel<<<1024, 256, 0, stream>>>(hVf_cur, dh, l1s + l*128, l1b + l*128, X1f, X1bf);
        gemm_kernel<2,0,false><<<16, 512, 0, stream>>>(X1bf, nullptr, nullptr, nullptr, p_f1, fb1 + l*128,
            Gbf, nullptr, nullptr, nullptr, nullptr, nullptr, nullptr);
        gemm_kernel<2,2,false><<<16, 512, 0, stream>>>(Gbf, nullptr, nullptr, nullptr, p_f2, fb2 + l*128,
            nullptr, nullptr, X1f, hVf_nxt, hVbf, l2s + l*128, l2b + l*128);

        // base vectors from updated h_V: b1e (this layer's edge MLP), b1n (next layer's node MLP)
        gemm_kernel<2,4,false><<<16, 512, 0, stream>>>(hVbf, nullptr, nullptr, nullptr, p_e1a, eb1 + l*128,
            nullptr, b1e, nullptr, nullptr, nullptr, nullptr, nullptr);
        if (l < 2)
            gemm_kernel<2,4,false><<<16, 512, 0, stream>>>(hVbf, nullptr, nullptr, nullptr,
                Wp + (size_t)(l+1) * 196608 + 163840, nb1 + (l+1)*128,
                nullptr, b1n, nullptr, nullptr, nullptr, nullptr, nullptr);

        // edge MLP + LN3 (M = 131072 edges)
        gemm_kernel<4,0,true ><<<512, 512, 0, stream>>>(nullptr, hVbf, hEbf, topo, p_e1, b1e,
            Hbf, nullptr, nullptr, nullptr, nullptr, nullptr, nullptr);
        gemm_kernel<2,0,false><<<512, 512, 0, stream>>>(Hbf, nullptr, nullptr, nullptr, p_e2, eb2 + l*128,
            Hbf, nullptr, nullptr, nullptr, nullptr, nullptr, nullptr);
        gemm_kernel<2,2,false><<<512, 512, 0, stream>>>(Hbf, nullptr, nullptr, nullptr, p_e3, eb3 + l*128,
            nullptr, nullptr, hEf_in, out_hE, hEbf, l3s + l*128, l3b + l*128);
    }
}